// Round 5
// baseline (1684.770 us; speedup 1.0000x reference)
//
#include <hip/hip_runtime.h>
#include <stdint.h>

#define NN 100000
#define DF 128
#define NE 3200000
#define NELEM (NN * DF)          // 12,800,000
#define NBLK ((NN + 255) / 256)  // 391 (scan blocks)
#define NBUCK 391                // row>>8 buckets (max row 99999>>8 = 390)
#define BCAP 12288               // bucket capacity (avg ~8192, 45-sigma margin)
#define OVF_CAP 65536

// ---------------- Threefry-2x32 (JAX-exact, partitionable, bits = x0^x1) ----
__host__ __device__ __forceinline__ void tf2x32(uint32_t& x0, uint32_t& x1,
                                                uint32_t k0, uint32_t k1) {
  uint32_t ks2 = k0 ^ k1 ^ 0x1BD11BDAu;
  x0 += k0; x1 += k1;
#define TF_RND(r) { x0 += x1; x1 = (x1 << (r)) | (x1 >> (32 - (r))); x1 ^= x0; }
  TF_RND(13) TF_RND(15) TF_RND(26) TF_RND(6)
  x0 += k1;  x1 += ks2 + 1u;
  TF_RND(17) TF_RND(29) TF_RND(16) TF_RND(24)
  x0 += ks2; x1 += k0 + 2u;
  TF_RND(13) TF_RND(15) TF_RND(26) TF_RND(6)
  x0 += k0;  x1 += k1 + 3u;
  TF_RND(17) TF_RND(29) TF_RND(16) TF_RND(24)
  x0 += k1;  x1 += ks2 + 4u;
  TF_RND(13) TF_RND(15) TF_RND(26) TF_RND(6)
  x0 += ks2; x1 += k0 + 5u;
#undef TF_RND
}

__device__ __forceinline__ bool keep_elem(uint32_t kA, uint32_t kB, uint32_t idx) {
  uint32_t x0 = 0u, x1 = idx;          // counter = (hi=0, lo=i)
  tf2x32(x0, x1, kA, kB);
  uint32_t bits = x0 ^ x1;             // partitionable combine (verified r2)
  float u = __uint_as_float((bits >> 9) | 0x3f800000u) - 1.0f;
  return u < 0.9f;
}

// ---------------- bf16 helpers (internal compression only) ----------------
__device__ __forceinline__ float bf2f(uint16_t u) {
  return __uint_as_float(((uint32_t)u) << 16);
}
__device__ __forceinline__ uint16_t f2bf(float f) {  // round-to-nearest-even
  uint32_t x = __float_as_uint(f);
  uint32_t r = x + 0x7fffu + ((x >> 16) & 1u);
  return (uint16_t)(r >> 16);
}

// ======================= phase 1: fused hist + bucket binfill =======================
// pack: row:17 (bits 47..63) | col:17 (bits 30..46) | (val_bits>>2):30 (bits 0..29)
__global__ __launch_bounds__(256) void binfill_kernel(
    const int4* __restrict__ rows4, const int4* __restrict__ cols4,
    const float4* __restrict__ vals4,
    int* __restrict__ row_cnt, int* __restrict__ bcnt, int* __restrict__ ovf_cnt,
    uint64_t* __restrict__ staging, uint64_t* __restrict__ ovf) {
  int e = blockIdx.x * 256 + threadIdx.x;
  if (e >= NE / 4) return;
  int4 r4 = rows4[e]; int4 c4 = cols4[e]; float4 v4 = vals4[e];
  int rr[4] = {r4.x, r4.y, r4.z, r4.w};
  int cc[4] = {c4.x, c4.y, c4.z, c4.w};
  float vv[4] = {v4.x, v4.y, v4.z, v4.w};
#pragma unroll
  for (int k = 0; k < 4; ++k) {
    int row = rr[k];
    atomicAdd(&row_cnt[row], 1);
    int b = row >> 8;
    int p = atomicAdd(&bcnt[b], 1);
    uint64_t packed = ((uint64_t)(uint32_t)row << 47) |
                      ((uint64_t)(uint32_t)cc[k] << 30) |
                      (uint64_t)(__float_as_uint(vv[k]) >> 2);
    if (p < BCAP) staging[(size_t)b * BCAP + p] = packed;
    else { int o = atomicAdd(ovf_cnt, 1); if (o < OVF_CAP) ovf[o] = packed; }
  }
}

// ======================= row_ptr scan (3 small kernels) =======================
__global__ __launch_bounds__(256) void blocksum_kernel(const int* __restrict__ cnt,
                                                       int* __restrict__ bsum) {
  __shared__ int lds[256];
  int i = blockIdx.x * 256 + threadIdx.x;
  lds[threadIdx.x] = (i < NN) ? cnt[i] : 0;
  __syncthreads();
#pragma unroll
  for (int off = 128; off > 0; off >>= 1) {
    if (threadIdx.x < off) lds[threadIdx.x] += lds[threadIdx.x + off];
    __syncthreads();
  }
  if (threadIdx.x == 0) bsum[blockIdx.x] = lds[0];
}

__global__ __launch_bounds__(512) void scan_bsums_kernel(const int* __restrict__ bsum,
                                                         int* __restrict__ boff) {
  __shared__ int lds[512];
  int tid = threadIdx.x;
  int v = (tid < NBLK) ? bsum[tid] : 0;
  lds[tid] = v;
  __syncthreads();
#pragma unroll
  for (int off = 1; off < 512; off <<= 1) {
    int add = (tid >= off) ? lds[tid - off] : 0;
    __syncthreads();
    lds[tid] += add;
    __syncthreads();
  }
  if (tid < NBLK) boff[tid] = lds[tid] - v;   // exclusive
}

__global__ __launch_bounds__(256) void localscan_kernel(const int* __restrict__ cnt,
                                                        const int* __restrict__ boff,
                                                        int* __restrict__ row_ptr,
                                                        int* __restrict__ row_fill) {
  __shared__ int lds[256];
  int i = blockIdx.x * 256 + threadIdx.x;
  int v = (i < NN) ? cnt[i] : 0;
  lds[threadIdx.x] = v;
  __syncthreads();
#pragma unroll
  for (int off = 1; off < 256; off <<= 1) {
    int add = (threadIdx.x >= off) ? lds[threadIdx.x - off] : 0;
    __syncthreads();
    lds[threadIdx.x] += add;
    __syncthreads();
  }
  if (i < NN) {
    int excl = boff[blockIdx.x] + lds[threadIdx.x] - v;
    row_ptr[i]  = excl;
    row_fill[i] = excl;
  }
  if (i == 0) row_ptr[NN] = NE;
}

// ======================= phase 2: bucket -> CSR scatter =======================
// grid = NBUCK+1 blocks; last block drains the overflow list.
// Each bucket's destinations span a 64KB CSR window -> L2-local, writes merge.
__global__ __launch_bounds__(512) void scatter_csr_kernel(
    const int* __restrict__ bcnt, const int* __restrict__ ovf_cnt,
    const uint64_t* __restrict__ staging, const uint64_t* __restrict__ ovf,
    int* __restrict__ row_fill, int2* __restrict__ csr) {
  int b = blockIdx.x;
  const uint64_t* src;
  int n;
  if (b < NBUCK) { src = staging + (size_t)b * BCAP; n = min(bcnt[b], BCAP); }
  else           { src = ovf;                        n = min(*ovf_cnt, OVF_CAP); }
  for (int i = threadIdx.x; i < n; i += 512) {
    uint64_t p = src[i];
    int row = (int)(p >> 47);
    int col = (int)((p >> 30) & 0x1FFFFu);
    uint32_t vb = ((uint32_t)p & 0x3FFFFFFFu) << 2;
    int pos = atomicAdd(&row_fill[row], 1);
    csr[pos] = make_int2(col, (int)vb);
  }
}

// ---------------- f32 -> bf16 table convert ----------------
__global__ __launch_bounds__(256) void convert_kernel(const float4* __restrict__ src,
                                                      ushort4* __restrict__ dst) {
  int i = blockIdx.x * 256 + threadIdx.x;
  if (i < NELEM / 4) {
    float4 v = src[i];
    dst[i] = make_ushort4(f2bf(v.x), f2bf(v.y), f2bf(v.z), f2bf(v.w));
  }
}

// ============== fused SpMM + residual + dropout + acc (bf16 gathers) ==============
template <int MODE>
__global__ __launch_bounds__(256) void spmm_layer_kernel(
    const int* __restrict__ row_ptr,
    const int2* __restrict__ csr,
    const ushort4* __restrict__ xb,     // gather table, bf16 [NN][32] x4
    const float4* __restrict__ qf,      // f32 q rows (MODE 0 only)
    ushort4* __restrict__ hb_out,
    float4* __restrict__ accv,
    uint32_t kA, uint32_t kB) {
  int r = blockIdx.x * 8 + (threadIdx.x >> 5);
  if (r >= NN) return;
  int lane = threadIdx.x & 31;
  int beg = row_ptr[r], end = row_ptr[r + 1];

  float4 s = make_float4(0.f, 0.f, 0.f, 0.f);
  int j = beg;
  int n8 = beg + ((end - beg) & ~7);
  for (; j < n8; j += 8) {   // 8 independent gathers in flight (MLP vs L3 latency)
    int2 cv[8]; ushort4 t[8];
#pragma unroll
    for (int u = 0; u < 8; ++u) cv[u] = csr[j + u];
#pragma unroll
    for (int u = 0; u < 8; ++u) t[u] = xb[(size_t)cv[u].x * 32 + lane];
#pragma unroll
    for (int u = 0; u < 8; ++u) {
      float v = __int_as_float(cv[u].y);
      s.x += v * bf2f(t[u].x); s.y += v * bf2f(t[u].y);
      s.z += v * bf2f(t[u].z); s.w += v * bf2f(t[u].w);
    }
  }
  for (; j < end; ++j) {
    int2 cv = csr[j];
    float v = __int_as_float(cv.y);
    ushort4 t = xb[(size_t)cv.x * 32 + lane];
    s.x += v * bf2f(t.x); s.y += v * bf2f(t.y); s.z += v * bf2f(t.z); s.w += v * bf2f(t.w);
  }

  int oi = r * 32 + lane;
  float pv[4];
  if (MODE == 0) {
    float4 p = qf[oi];
    pv[0] = p.x; pv[1] = p.y; pv[2] = p.z; pv[3] = p.w;
  } else {
    ushort4 p = xb[oi];
    pv[0] = bf2f(p.x); pv[1] = bf2f(p.y); pv[2] = bf2f(p.z); pv[3] = bf2f(p.w);
  }
  uint32_t base = (uint32_t)r * 128u + (uint32_t)lane * 4u;
  float sv[4] = {s.x, s.y, s.z, s.w};
  float h[4];
#pragma unroll
  for (int k = 0; k < 4; ++k) {
    float t = sv[k] + pv[k];
    h[k] = keep_elem(kA, kB, base + (uint32_t)k) ? t * (1.0f / 0.9f) : 0.0f;
  }
  if (MODE == 0) {
    accv[oi] = make_float4(pv[0] + h[0], pv[1] + h[1], pv[2] + h[2], pv[3] + h[3]);
    hb_out[oi] = make_ushort4(f2bf(h[0]), f2bf(h[1]), f2bf(h[2]), f2bf(h[3]));
  } else if (MODE == 1) {
    float4 a = accv[oi];
    accv[oi] = make_float4(a.x + h[0], a.y + h[1], a.z + h[2], a.w + h[3]);
    hb_out[oi] = make_ushort4(f2bf(h[0]), f2bf(h[1]), f2bf(h[2]), f2bf(h[3]));
  } else {
    float4 a = accv[oi];
    accv[oi] = make_float4((a.x + h[0]) * 0.25f, (a.y + h[1]) * 0.25f,
                           (a.z + h[2]) * 0.25f, (a.w + h[3]) * 0.25f);
  }
}

// ======================= launch =======================
extern "C" void kernel_launch(void* const* d_in, const int* in_sizes, int n_in,
                              void* d_out, int out_size, void* d_ws, size_t ws_size,
                              hipStream_t stream) {
  const float* q   = (const float*)d_in[0];
  const int* rows  = (const int*)d_in[1];
  const int* cols  = (const int*)d_in[2];
  const float* vls = (const float*)d_in[3];
  float* acc = (float*)d_out;

  // layer keys: fold_in(key(42), layer) = threefry2x32((0,42),(0,layer))
  uint32_t kA[3], kB[3];
  for (int l = 0; l < 3; ++l) {
    uint32_t x0 = 0u, x1 = (uint32_t)l;
    tf2x32(x0, x1, 0u, 42u);
    kA[l] = x0; kB[l] = x1;
  }

  // ---- workspace layout (~104 MB) ----
  uint16_t* xb_q = (uint16_t*)d_ws;               // NELEM bf16 (25.6 MB)
  uint16_t* hb1  = xb_q + NELEM;                  // NELEM bf16
  uint16_t* hb2  = hb1 + NELEM;                   // NELEM bf16
  // bucket staging (38.4 MB) aliases hb1+hb2 (51.2 MB) — dead before spmm0 runs
  uint64_t* staging = (uint64_t*)hb1;
  int2* csr_cv   = (int2*)(hb2 + NELEM);          // NE (25.6 MB)
  int* row_ptr   = (int*)(csr_cv + NE);           // NN+1
  int* bsum      = row_ptr + NN + 1;              // NBLK
  int* boff      = bsum + NBLK;                   // NBLK
  int* row_fill  = boff + NBLK;                   // NN
  int* row_cnt   = row_fill + NN;                 // NN   -- zeroed region start
  int* bcnt      = row_cnt + NN;                  // NBUCK
  int* ovf_cnt   = bcnt + NBUCK;                  // 1
  uint64_t* ovf  = (uint64_t*)(((uintptr_t)(ovf_cnt + 1) + 7) & ~(uintptr_t)7);

  dim3 blk(256);

  hipMemsetAsync(row_cnt, 0, (size_t)(NN + NBUCK + 1) * 4, stream);
  convert_kernel<<<NELEM / 4 / 256, blk, 0, stream>>>((const float4*)q, (ushort4*)xb_q);
  binfill_kernel<<<NE / 4 / 256, blk, 0, stream>>>(
      (const int4*)rows, (const int4*)cols, (const float4*)vls,
      row_cnt, bcnt, ovf_cnt, staging, ovf);
  blocksum_kernel<<<NBLK, blk, 0, stream>>>(row_cnt, bsum);
  scan_bsums_kernel<<<1, 512, 0, stream>>>(bsum, boff);
  localscan_kernel<<<NBLK, blk, 0, stream>>>(row_cnt, boff, row_ptr, row_fill);
  scatter_csr_kernel<<<NBUCK + 1, 512, 0, stream>>>(
      bcnt, ovf_cnt, staging, ovf, row_fill, csr_cv);

  const int grid = (NN + 7) / 8;
  spmm_layer_kernel<0><<<grid, blk, 0, stream>>>(
      row_ptr, csr_cv, (const ushort4*)xb_q, (const float4*)q,
      (ushort4*)hb1, (float4*)acc, kA[0], kB[0]);
  spmm_layer_kernel<1><<<grid, blk, 0, stream>>>(
      row_ptr, csr_cv, (const ushort4*)hb1, nullptr,
      (ushort4*)hb2, (float4*)acc, kA[1], kB[1]);
  spmm_layer_kernel<2><<<grid, blk, 0, stream>>>(
      row_ptr, csr_cv, (const ushort4*)hb2, nullptr,
      nullptr, (float4*)acc, kA[2], kB[2]);
}

// Round 6
// 491.959 us; speedup vs baseline: 3.4246x; 3.4246x over previous
//
#include <hip/hip_runtime.h>
#include <stdint.h>

#define NN 100000
#define DF 128
#define NE 3200000
#define NELEM (NN * DF)          // 12,800,000
#define NBUCK 391                // row>>8 buckets (max row 99999>>8 = 390)
#define BCAP 12288               // bucket staging capacity (avg ~8184, +45 sigma)
#define BSTRIDE 16               // bcnt padding: one counter per 64B line
#define EPB 4096                 // edges per binfill block (16 per thread)
#define NBINBLK ((NE + EPB - 1) / EPB)   // 782
#define OVF_CAP 65536

// ---------------- Threefry-2x32 (JAX-exact, partitionable, bits = x0^x1) ----
__host__ __device__ __forceinline__ void tf2x32(uint32_t& x0, uint32_t& x1,
                                                uint32_t k0, uint32_t k1) {
  uint32_t ks2 = k0 ^ k1 ^ 0x1BD11BDAu;
  x0 += k0; x1 += k1;
#define TF_RND(r) { x0 += x1; x1 = (x1 << (r)) | (x1 >> (32 - (r))); x1 ^= x0; }
  TF_RND(13) TF_RND(15) TF_RND(26) TF_RND(6)
  x0 += k1;  x1 += ks2 + 1u;
  TF_RND(17) TF_RND(29) TF_RND(16) TF_RND(24)
  x0 += ks2; x1 += k0 + 2u;
  TF_RND(13) TF_RND(15) TF_RND(26) TF_RND(6)
  x0 += k0;  x1 += k1 + 3u;
  TF_RND(17) TF_RND(29) TF_RND(16) TF_RND(24)
  x0 += k1;  x1 += ks2 + 4u;
  TF_RND(13) TF_RND(15) TF_RND(26) TF_RND(6)
  x0 += ks2; x1 += k0 + 5u;
#undef TF_RND
}

__device__ __forceinline__ bool keep_elem(uint32_t kA, uint32_t kB, uint32_t idx) {
  uint32_t x0 = 0u, x1 = idx;          // counter = (hi=0, lo=i)
  tf2x32(x0, x1, kA, kB);
  uint32_t bits = x0 ^ x1;             // partitionable combine (verified r2)
  float u = __uint_as_float((bits >> 9) | 0x3f800000u) - 1.0f;
  return u < 0.9f;
}

// ---------------- bf16 helpers (internal compression only) ----------------
__device__ __forceinline__ float bf2f(uint16_t u) {
  return __uint_as_float(((uint32_t)u) << 16);
}
__device__ __forceinline__ uint16_t f2bf(float f) {  // round-to-nearest-even
  uint32_t x = __float_as_uint(f);
  uint32_t r = x + 0x7fffu + ((x >> 16) & 1u);
  return (uint16_t)(r >> 16);
}

// pack: row:17 (bits 47..63) | col:17 (bits 30..46) | (val_bits>>2):30 (bits 0..29)
__device__ __forceinline__ uint64_t pack_edge(int row, int col, float val) {
  return ((uint64_t)(uint32_t)row << 47) | ((uint64_t)(uint32_t)col << 30) |
         (uint64_t)(__float_as_uint(val) >> 2);
}

// ============ phase 1: block-local LDS binning, chunked claims ============
__global__ __launch_bounds__(256) void binfill2_kernel(
    const int* __restrict__ rows, const int* __restrict__ cols,
    const float* __restrict__ vals,
    int* __restrict__ bcnt,            // [NBUCK*BSTRIDE], line-padded
    int* __restrict__ ovf_cnt, int* __restrict__ row_cnt_ovf,
    uint64_t* __restrict__ staging, uint64_t* __restrict__ ovf) {
  __shared__ int lcnt[NBUCK];
  __shared__ int lcur[NBUCK];
  int t = threadIdx.x;
  for (int i = t; i < NBUCK; i += 256) lcnt[i] = 0;
  __syncthreads();

  int base = blockIdx.x * EPB;
  int rr[16];
  // phase A: LDS histogram of this block's 4096 edges
#pragma unroll
  for (int k = 0; k < 16; ++k) {
    int e = base + k * 256 + t;
    rr[k] = (e < NE) ? rows[e] : -1;
    if (rr[k] >= 0) atomicAdd(&lcnt[rr[k] >> 8], 1);
  }
  __syncthreads();
  // phase B: one contiguous chunk claim per bucket (391 global atomics/block)
  for (int i = t; i < NBUCK; i += 256)
    lcur[i] = atomicAdd(&bcnt[i * BSTRIDE], lcnt[i]);
  __syncthreads();
  // phase C: write edges densely into block-owned chunks
#pragma unroll
  for (int k = 0; k < 16; ++k) {
    if (rr[k] < 0) continue;
    int e = base + k * 256 + t;
    int row = rr[k];
    int b = row >> 8;
    uint64_t packed = pack_edge(row, cols[e], vals[e]);
    int slot = atomicAdd(&lcur[b], 1);
    if (slot < BCAP) {
      staging[(size_t)b * BCAP + slot] = packed;
    } else {
      int o = atomicAdd(ovf_cnt, 1);
      if (o < OVF_CAP) ovf[o] = packed;
      atomicAdd(&row_cnt_ovf[row], 1);
    }
  }
}

// ============ bucket-offset scan (391 values, 1 block) ============
__global__ __launch_bounds__(512) void scan_bsums_kernel(const int* __restrict__ bcnt,
                                                         int* __restrict__ boff) {
  __shared__ int lds[512];
  int tid = threadIdx.x;
  int v = (tid < NBUCK) ? bcnt[tid * BSTRIDE] : 0;
  lds[tid] = v;
  __syncthreads();
#pragma unroll
  for (int off = 1; off < 512; off <<= 1) {
    int add = (tid >= off) ? lds[tid - off] : 0;
    __syncthreads();
    lds[tid] += add;
    __syncthreads();
  }
  if (tid < NBUCK) boff[tid] = lds[tid] - v;   // exclusive
}

// ============ phase 2: bucket -> CSR (block b owns rows [b*256, b*256+256)) ====
// Emits row_ptr (in-LDS scan), CSR records (64KB window, L2-merged), row_fill.
__global__ __launch_bounds__(256) void scatter_csr2_kernel(
    const int* __restrict__ bcnt, const int* __restrict__ boff,
    const int* __restrict__ row_cnt_ovf,
    const uint64_t* __restrict__ staging,
    int* __restrict__ row_ptr, int* __restrict__ row_fill,
    int2* __restrict__ csr) {
  __shared__ int scnt[256];      // staged count per local row
  __shared__ int lds[256];       // scan workspace
  __shared__ int lcur[256];      // write cursors
  int b = blockIdx.x;
  int t = threadIdx.x;
  int g = b * 256 + t;           // global row
  int n_tot = bcnt[b * BSTRIDE];
  int n_stg = min(n_tot, BCAP);
  const uint64_t* src = staging + (size_t)b * BCAP;

  scnt[t] = 0;
  __syncthreads();
  // stage 1: histogram of staged edges by local row
  for (int i = t; i < n_stg; i += 256)
    atomicAdd(&scnt[(int)(src[i] >> 47) & 255], 1);
  __syncthreads();
  // stage 2: exclusive scan of total counts (staged + overflowed)
  int ovfc = (g < NN) ? row_cnt_ovf[g] : 0;
  int v = scnt[t] + ovfc;
  lds[t] = v;
  __syncthreads();
#pragma unroll
  for (int off = 1; off < 256; off <<= 1) {
    int add = (t >= off) ? lds[t - off] : 0;
    __syncthreads();
    lds[t] += add;
    __syncthreads();
  }
  int excl = lds[t] - v;
  int bo = boff[b];
  if (g <= NN) row_ptr[g] = bo + excl;         // covers row_ptr[NN]=NE via blk 390
  if (g < NN) row_fill[g] = bo + excl + scnt[t];  // ovf edges append here
  lcur[t] = excl;
  __syncthreads();
  // stage 3: scatter staged edges into the bucket's CSR window
  for (int i = t; i < n_stg; i += 256) {
    uint64_t p = src[i];
    int rl = (int)(p >> 47) & 255;
    int col = (int)((p >> 30) & 0x1FFFFu);
    uint32_t vb = ((uint32_t)p & 0x3FFFFFFFu) << 2;
    int pos = bo + atomicAdd(&lcur[rl], 1);
    csr[pos] = make_int2(col, (int)vb);
  }
}

// ============ overflow drain (normally 0 edges) ============
__global__ __launch_bounds__(256) void ovf_drain_kernel(
    const int* __restrict__ ovf_cnt, const uint64_t* __restrict__ ovf,
    int* __restrict__ row_fill, int2* __restrict__ csr) {
  int n = min(*ovf_cnt, OVF_CAP);
  for (int i = threadIdx.x; i < n; i += 256) {
    uint64_t p = ovf[i];
    int row = (int)(p >> 47);
    int col = (int)((p >> 30) & 0x1FFFFu);
    uint32_t vb = ((uint32_t)p & 0x3FFFFFFFu) << 2;
    int pos = atomicAdd(&row_fill[row], 1);
    csr[pos] = make_int2(col, (int)vb);
  }
}

// ---------------- f32 -> bf16 table convert ----------------
__global__ __launch_bounds__(256) void convert_kernel(const float4* __restrict__ src,
                                                      ushort4* __restrict__ dst) {
  int i = blockIdx.x * 256 + threadIdx.x;
  if (i < NELEM / 4) {
    float4 v = src[i];
    dst[i] = make_ushort4(f2bf(v.x), f2bf(v.y), f2bf(v.z), f2bf(v.w));
  }
}

// ============== fused SpMM + residual + dropout + acc (bf16 gathers) ==============
template <int MODE>
__global__ __launch_bounds__(256) void spmm_layer_kernel(
    const int* __restrict__ row_ptr,
    const int2* __restrict__ csr,
    const ushort4* __restrict__ xb,     // gather table, bf16 [NN][32] x4
    const float4* __restrict__ qf,      // f32 q rows (MODE 0 only)
    ushort4* __restrict__ hb_out,
    float4* __restrict__ accv,
    uint32_t kA, uint32_t kB) {
  int r = blockIdx.x * 8 + (threadIdx.x >> 5);
  if (r >= NN) return;
  int lane = threadIdx.x & 31;
  int beg = row_ptr[r], end = row_ptr[r + 1];

  float4 s = make_float4(0.f, 0.f, 0.f, 0.f);
  int j = beg;
  int n8 = beg + ((end - beg) & ~7);
  for (; j < n8; j += 8) {   // 8 independent gathers in flight (MLP vs L3 latency)
    int2 cv[8]; ushort4 t[8];
#pragma unroll
    for (int u = 0; u < 8; ++u) cv[u] = csr[j + u];
#pragma unroll
    for (int u = 0; u < 8; ++u) t[u] = xb[(size_t)cv[u].x * 32 + lane];
#pragma unroll
    for (int u = 0; u < 8; ++u) {
      float v = __int_as_float(cv[u].y);
      s.x += v * bf2f(t[u].x); s.y += v * bf2f(t[u].y);
      s.z += v * bf2f(t[u].z); s.w += v * bf2f(t[u].w);
    }
  }
  for (; j < end; ++j) {
    int2 cv = csr[j];
    float v = __int_as_float(cv.y);
    ushort4 t = xb[(size_t)cv.x * 32 + lane];
    s.x += v * bf2f(t.x); s.y += v * bf2f(t.y); s.z += v * bf2f(t.z); s.w += v * bf2f(t.w);
  }

  int oi = r * 32 + lane;
  float pv[4];
  if (MODE == 0) {
    float4 p = qf[oi];
    pv[0] = p.x; pv[1] = p.y; pv[2] = p.z; pv[3] = p.w;
  } else {
    ushort4 p = xb[oi];
    pv[0] = bf2f(p.x); pv[1] = bf2f(p.y); pv[2] = bf2f(p.z); pv[3] = bf2f(p.w);
  }
  uint32_t base = (uint32_t)r * 128u + (uint32_t)lane * 4u;
  float sv[4] = {s.x, s.y, s.z, s.w};
  float h[4];
#pragma unroll
  for (int k = 0; k < 4; ++k) {
    float t = sv[k] + pv[k];
    h[k] = keep_elem(kA, kB, base + (uint32_t)k) ? t * (1.0f / 0.9f) : 0.0f;
  }
  if (MODE == 0) {
    accv[oi] = make_float4(pv[0] + h[0], pv[1] + h[1], pv[2] + h[2], pv[3] + h[3]);
    hb_out[oi] = make_ushort4(f2bf(h[0]), f2bf(h[1]), f2bf(h[2]), f2bf(h[3]));
  } else if (MODE == 1) {
    float4 a = accv[oi];
    accv[oi] = make_float4(a.x + h[0], a.y + h[1], a.z + h[2], a.w + h[3]);
    hb_out[oi] = make_ushort4(f2bf(h[0]), f2bf(h[1]), f2bf(h[2]), f2bf(h[3]));
  } else {
    float4 a = accv[oi];
    accv[oi] = make_float4((a.x + h[0]) * 0.25f, (a.y + h[1]) * 0.25f,
                           (a.z + h[2]) * 0.25f, (a.w + h[3]) * 0.25f);
  }
}

// ======================= launch =======================
extern "C" void kernel_launch(void* const* d_in, const int* in_sizes, int n_in,
                              void* d_out, int out_size, void* d_ws, size_t ws_size,
                              hipStream_t stream) {
  const float* q   = (const float*)d_in[0];
  const int* rows  = (const int*)d_in[1];
  const int* cols  = (const int*)d_in[2];
  const float* vls = (const float*)d_in[3];
  float* acc = (float*)d_out;

  // layer keys: fold_in(key(42), layer) = threefry2x32((0,42),(0,layer))
  uint32_t kA[3], kB[3];
  for (int l = 0; l < 3; ++l) {
    uint32_t x0 = 0u, x1 = (uint32_t)l;
    tf2x32(x0, x1, 0u, 42u);
    kA[l] = x0; kB[l] = x1;
  }

  // ---- workspace layout (~104.5 MB; ws >= 129 MB per r3) ----
  uint16_t* xb_q = (uint16_t*)d_ws;               // NELEM bf16 (25.6 MB)
  uint16_t* hb1  = xb_q + NELEM;                  // NELEM bf16 (25.6 MB)
  uint16_t* hb2  = hb1 + NELEM;                   // NELEM bf16 (25.6 MB)
  uint64_t* staging = (uint64_t*)hb1;             // 38.4 MB, aliases hb1+hb2 (dead until spmm0)
  int2* csr_cv   = (int2*)(hb2 + NELEM);          // NE (25.6 MB)
  int* row_ptr   = (int*)(csr_cv + NE);           // NN+1
  int* boff      = row_ptr + NN + 1;              // NBUCK
  int* row_fill  = boff + NBUCK;                  // NN
  int* row_cnt_ovf = row_fill + NN;               // NN      -- zero region start
  int* bcnt      = row_cnt_ovf + NN;              // NBUCK*BSTRIDE
  int* ovf_cnt   = bcnt + NBUCK * BSTRIDE;        // 1       -- zero region end
  uint64_t* ovf  = (uint64_t*)(((uintptr_t)(ovf_cnt + 1) + 7) & ~(uintptr_t)7);

  dim3 blk(256);

  hipMemsetAsync(row_cnt_ovf, 0, (size_t)(NN + NBUCK * BSTRIDE + 1) * 4, stream);
  convert_kernel<<<NELEM / 4 / 256, blk, 0, stream>>>((const float4*)q, (ushort4*)xb_q);
  binfill2_kernel<<<NBINBLK, blk, 0, stream>>>(
      rows, cols, vls, bcnt, ovf_cnt, row_cnt_ovf, staging, ovf);
  scan_bsums_kernel<<<1, 512, 0, stream>>>(bcnt, boff);
  scatter_csr2_kernel<<<NBUCK, blk, 0, stream>>>(
      bcnt, boff, row_cnt_ovf, staging, row_ptr, row_fill, csr_cv);
  ovf_drain_kernel<<<1, blk, 0, stream>>>(ovf_cnt, ovf, row_fill, csr_cv);

  const int grid = (NN + 7) / 8;
  spmm_layer_kernel<0><<<grid, blk, 0, stream>>>(
      row_ptr, csr_cv, (const ushort4*)xb_q, (const float4*)q,
      (ushort4*)hb1, (float4*)acc, kA[0], kB[0]);
  spmm_layer_kernel<1><<<grid, blk, 0, stream>>>(
      row_ptr, csr_cv, (const ushort4*)hb1, nullptr,
      (ushort4*)hb2, (float4*)acc, kA[1], kB[1]);
  spmm_layer_kernel<2><<<grid, blk, 0, stream>>>(
      row_ptr, csr_cv, (const ushort4*)hb2, nullptr,
      nullptr, (float4*)acc, kA[2], kB[2]);
}

// Round 7
// 475.710 us; speedup vs baseline: 3.5416x; 1.0342x over previous
//
#include <hip/hip_runtime.h>
#include <stdint.h>

#define NN 100000
#define DF 128
#define NE 3200000
#define NELEM (NN * DF)          // 12,800,000
#define NBUCK 391                // row>>8 buckets (max row 99999>>8 = 390)
#define BCAP 12288               // bucket staging capacity (avg ~8184, +45 sigma)
#define BSTRIDE 16               // bcnt padding: one counter per 64B line
#define EPB 4096                 // edges per binfill block (16 per thread)
#define NBINBLK ((NE + EPB - 1) / EPB)   // 782
#define OVF_CAP 65536

// ---------------- Threefry-2x32 (JAX-exact, partitionable, bits = x0^x1) ----
__host__ __device__ __forceinline__ void tf2x32(uint32_t& x0, uint32_t& x1,
                                                uint32_t k0, uint32_t k1) {
  uint32_t ks2 = k0 ^ k1 ^ 0x1BD11BDAu;
  x0 += k0; x1 += k1;
#define TF_RND(r) { x0 += x1; x1 = (x1 << (r)) | (x1 >> (32 - (r))); x1 ^= x0; }
  TF_RND(13) TF_RND(15) TF_RND(26) TF_RND(6)
  x0 += k1;  x1 += ks2 + 1u;
  TF_RND(17) TF_RND(29) TF_RND(16) TF_RND(24)
  x0 += ks2; x1 += k0 + 2u;
  TF_RND(13) TF_RND(15) TF_RND(26) TF_RND(6)
  x0 += k0;  x1 += k1 + 3u;
  TF_RND(17) TF_RND(29) TF_RND(16) TF_RND(24)
  x0 += k1;  x1 += ks2 + 4u;
  TF_RND(13) TF_RND(15) TF_RND(26) TF_RND(6)
  x0 += ks2; x1 += k0 + 5u;
#undef TF_RND
}

__device__ __forceinline__ bool keep_elem(uint32_t kA, uint32_t kB, uint32_t idx) {
  uint32_t x0 = 0u, x1 = idx;          // counter = (hi=0, lo=i)
  tf2x32(x0, x1, kA, kB);
  uint32_t bits = x0 ^ x1;             // partitionable combine (verified r2)
  float u = __uint_as_float((bits >> 9) | 0x3f800000u) - 1.0f;
  return u < 0.9f;
}

// ---------------- bf16 helpers (internal compression only) ----------------
__device__ __forceinline__ uint16_t f2bf(float f) {  // round-to-nearest-even
  uint32_t x = __float_as_uint(f);
  uint32_t r = x + 0x7fffu + ((x >> 16) & 1u);
  return (uint16_t)(r >> 16);
}

// pack: row:17 (bits 47..63) | col:17 (bits 30..46) | (val_bits>>2):30 (bits 0..29)
__device__ __forceinline__ uint64_t pack_edge(int row, int col, float val) {
  return ((uint64_t)(uint32_t)row << 47) | ((uint64_t)(uint32_t)col << 30) |
         (uint64_t)(__float_as_uint(val) >> 2);
}

// ============ phase 1: block-local LDS binning, chunked claims ============
__global__ __launch_bounds__(256) void binfill2_kernel(
    const int* __restrict__ rows, const int* __restrict__ cols,
    const float* __restrict__ vals,
    int* __restrict__ bcnt,            // [NBUCK*BSTRIDE], line-padded
    int* __restrict__ ovf_cnt, int* __restrict__ row_cnt_ovf,
    uint64_t* __restrict__ staging, uint64_t* __restrict__ ovf) {
  __shared__ int lcnt[NBUCK];
  __shared__ int lcur[NBUCK];
  int t = threadIdx.x;
  for (int i = t; i < NBUCK; i += 256) lcnt[i] = 0;
  __syncthreads();

  int base = blockIdx.x * EPB;
  int rr[16];
  // phase A: LDS histogram of this block's 4096 edges
#pragma unroll
  for (int k = 0; k < 16; ++k) {
    int e = base + k * 256 + t;
    rr[k] = (e < NE) ? rows[e] : -1;
    if (rr[k] >= 0) atomicAdd(&lcnt[rr[k] >> 8], 1);
  }
  __syncthreads();
  // phase B: one contiguous chunk claim per bucket (391 global atomics/block)
  for (int i = t; i < NBUCK; i += 256)
    lcur[i] = atomicAdd(&bcnt[i * BSTRIDE], lcnt[i]);
  __syncthreads();
  // phase C: write edges densely into block-owned chunks
#pragma unroll
  for (int k = 0; k < 16; ++k) {
    if (rr[k] < 0) continue;
    int e = base + k * 256 + t;
    int row = rr[k];
    int b = row >> 8;
    uint64_t packed = pack_edge(row, cols[e], vals[e]);
    int slot = atomicAdd(&lcur[b], 1);
    if (slot < BCAP) {
      staging[(size_t)b * BCAP + slot] = packed;
    } else {
      int o = atomicAdd(ovf_cnt, 1);
      if (o < OVF_CAP) ovf[o] = packed;
      atomicAdd(&row_cnt_ovf[row], 1);
    }
  }
}

// ============ bucket-offset scan (391 values, 1 block) ============
__global__ __launch_bounds__(512) void scan_bsums_kernel(const int* __restrict__ bcnt,
                                                         int* __restrict__ boff) {
  __shared__ int lds[512];
  int tid = threadIdx.x;
  int v = (tid < NBUCK) ? bcnt[tid * BSTRIDE] : 0;
  lds[tid] = v;
  __syncthreads();
#pragma unroll
  for (int off = 1; off < 512; off <<= 1) {
    int add = (tid >= off) ? lds[tid - off] : 0;
    __syncthreads();
    lds[tid] += add;
    __syncthreads();
  }
  if (tid < NBUCK) boff[tid] = lds[tid] - v;   // exclusive
}

// ============ phase 2: bucket -> CSR (block b owns rows [b*256, b*256+256)) ====
__global__ __launch_bounds__(256) void scatter_csr2_kernel(
    const int* __restrict__ bcnt, const int* __restrict__ boff,
    const int* __restrict__ row_cnt_ovf,
    const uint64_t* __restrict__ staging,
    int* __restrict__ row_ptr, int* __restrict__ row_fill,
    int2* __restrict__ csr) {
  __shared__ int scnt[256];      // staged count per local row
  __shared__ int lds[256];       // scan workspace
  __shared__ int lcur[256];      // write cursors
  int b = blockIdx.x;
  int t = threadIdx.x;
  int g = b * 256 + t;           // global row
  int n_tot = bcnt[b * BSTRIDE];
  int n_stg = min(n_tot, BCAP);
  const uint64_t* src = staging + (size_t)b * BCAP;

  scnt[t] = 0;
  __syncthreads();
  for (int i = t; i < n_stg; i += 256)
    atomicAdd(&scnt[(int)(src[i] >> 47) & 255], 1);
  __syncthreads();
  int ovfc = (g < NN) ? row_cnt_ovf[g] : 0;
  int v = scnt[t] + ovfc;
  lds[t] = v;
  __syncthreads();
#pragma unroll
  for (int off = 1; off < 256; off <<= 1) {
    int add = (t >= off) ? lds[t - off] : 0;
    __syncthreads();
    lds[t] += add;
    __syncthreads();
  }
  int excl = lds[t] - v;
  int bo = boff[b];
  if (g <= NN) row_ptr[g] = bo + excl;
  if (g < NN) row_fill[g] = bo + excl + scnt[t];
  lcur[t] = excl;
  __syncthreads();
  for (int i = t; i < n_stg; i += 256) {
    uint64_t p = src[i];
    int rl = (int)(p >> 47) & 255;
    int col = (int)((p >> 30) & 0x1FFFFu);
    uint32_t vb = ((uint32_t)p & 0x3FFFFFFFu) << 2;
    int pos = bo + atomicAdd(&lcur[rl], 1);
    csr[pos] = make_int2(col, (int)vb);
  }
}

// ============ overflow drain (normally 0 edges) ============
__global__ __launch_bounds__(256) void ovf_drain_kernel(
    const int* __restrict__ ovf_cnt, const uint64_t* __restrict__ ovf,
    int* __restrict__ row_fill, int2* __restrict__ csr) {
  int n = min(*ovf_cnt, OVF_CAP);
  for (int i = threadIdx.x; i < n; i += 256) {
    uint64_t p = ovf[i];
    int row = (int)(p >> 47);
    int col = (int)((p >> 30) & 0x1FFFFu);
    uint32_t vb = ((uint32_t)p & 0x3FFFFFFFu) << 2;
    int pos = atomicAdd(&row_fill[row], 1);
    csr[pos] = make_int2(col, (int)vb);
  }
}

// ---------------- f32 -> bf16 table convert ----------------
__global__ __launch_bounds__(256) void convert_kernel(const float4* __restrict__ src,
                                                      ushort4* __restrict__ dst) {
  int i = blockIdx.x * 256 + threadIdx.x;
  if (i < NELEM / 4) {
    float4 v = src[i];
    dst[i] = make_ushort4(f2bf(v.x), f2bf(v.y), f2bf(v.z), f2bf(v.w));
  }
}

// ============== fused SpMM + residual + dropout + acc ==============
// One wave64 per row; lane owns one bf16x2 dword (features 2*lane, 2*lane+1).
// Row index forced wave-uniform (readfirstlane) => CSR stream and gather row
// bases are SGPR-resident: s_load for csr, saddr-form gathers, no per-edge
// vector address math.
template <int MODE>
__global__ __launch_bounds__(256) void spmm_layer_kernel(
    const int* __restrict__ row_ptr,
    const int2* __restrict__ csr,
    const uint32_t* __restrict__ xb,    // bf16x2 table, [NN*64] dwords
    const float2* __restrict__ qf,      // f32 q rows (MODE 0 only)
    uint32_t* __restrict__ hb_out,      // bf16x2 out (MODE 0/1)
    float2* __restrict__ accv,
    uint32_t kA, uint32_t kB) {
  int r = __builtin_amdgcn_readfirstlane(blockIdx.x * 4 + (threadIdx.x >> 6));
  if (r >= NN) return;                  // grid exact (NN % 4 == 0)
  int lane = threadIdx.x & 63;
  int beg = row_ptr[r], end = row_ptr[r + 1];   // uniform -> scalar loads

  float s0a = 0.f, s1a = 0.f, s0b = 0.f, s1b = 0.f;
  int j = beg;
  int n8 = beg + ((end - beg) & ~7);
  for (; j < n8; j += 8) {              // 8 gathers in flight
    int2 cv[8];
#pragma unroll
    for (int u = 0; u < 8; ++u) cv[u] = csr[j + u];   // uniform -> s_load
    uint32_t t[8];
#pragma unroll
    for (int u = 0; u < 8; ++u) {
      const uint32_t* p = xb + (size_t)cv[u].x * 64;  // SGPR base
      t[u] = p[lane];                                 // saddr gather, 4B/lane
    }
#pragma unroll
    for (int u = 0; u < 8; ++u) {
      float v = __int_as_float(cv[u].y);
      float lo = __uint_as_float(t[u] << 16);
      float hi = __uint_as_float(t[u] & 0xFFFF0000u);
      if (u & 1) { s0b += v * lo; s1b += v * hi; }
      else       { s0a += v * lo; s1a += v * hi; }
    }
  }
  for (; j < end; ++j) {
    int2 cv = csr[j];
    float v = __int_as_float(cv.y);
    const uint32_t* p = xb + (size_t)cv.x * 64;
    uint32_t t = p[lane];
    s0a += v * __uint_as_float(t << 16);
    s1a += v * __uint_as_float(t & 0xFFFF0000u);
  }
  float s0 = s0a + s0b, s1 = s1a + s1b;

  int oi = r * 64 + lane;
  float p0, p1;
  if (MODE == 0) {
    float2 p = qf[oi];
    p0 = p.x; p1 = p.y;
  } else {
    uint32_t p = xb[oi];
    p0 = __uint_as_float(p << 16);
    p1 = __uint_as_float(p & 0xFFFF0000u);
  }
  uint32_t base = (uint32_t)r * 128u + (uint32_t)lane * 2u;
  float t0 = s0 + p0, t1 = s1 + p1;
  float h0 = keep_elem(kA, kB, base)      ? t0 * (1.0f / 0.9f) : 0.0f;
  float h1 = keep_elem(kA, kB, base + 1u) ? t1 * (1.0f / 0.9f) : 0.0f;

  if (MODE == 0) {
    accv[oi] = make_float2(p0 + h0, p1 + h1);
    hb_out[oi] = (uint32_t)f2bf(h0) | ((uint32_t)f2bf(h1) << 16);
  } else if (MODE == 1) {
    float2 a = accv[oi];
    accv[oi] = make_float2(a.x + h0, a.y + h1);
    hb_out[oi] = (uint32_t)f2bf(h0) | ((uint32_t)f2bf(h1) << 16);
  } else {
    float2 a = accv[oi];
    accv[oi] = make_float2((a.x + h0) * 0.25f, (a.y + h1) * 0.25f);
  }
}

// ======================= launch =======================
extern "C" void kernel_launch(void* const* d_in, const int* in_sizes, int n_in,
                              void* d_out, int out_size, void* d_ws, size_t ws_size,
                              hipStream_t stream) {
  const float* q   = (const float*)d_in[0];
  const int* rows  = (const int*)d_in[1];
  const int* cols  = (const int*)d_in[2];
  const float* vls = (const float*)d_in[3];
  float* acc = (float*)d_out;

  // layer keys: fold_in(key(42), layer) = threefry2x32((0,42),(0,layer))
  uint32_t kA[3], kB[3];
  for (int l = 0; l < 3; ++l) {
    uint32_t x0 = 0u, x1 = (uint32_t)l;
    tf2x32(x0, x1, 0u, 42u);
    kA[l] = x0; kB[l] = x1;
  }

  // ---- workspace layout (~104.5 MB) ----
  uint16_t* xb_q = (uint16_t*)d_ws;               // NELEM bf16 (25.6 MB)
  uint16_t* hb1  = xb_q + NELEM;                  // NELEM bf16 (25.6 MB)
  uint16_t* hb2  = hb1 + NELEM;                   // NELEM bf16 (25.6 MB)
  uint64_t* staging = (uint64_t*)hb1;             // 38.4 MB, aliases hb1+hb2 (dead until spmm0)
  int2* csr_cv   = (int2*)(hb2 + NELEM);          // NE (25.6 MB)
  int* row_ptr   = (int*)(csr_cv + NE);           // NN+1
  int* boff      = row_ptr + NN + 1;              // NBUCK
  int* row_fill  = boff + NBUCK;                  // NN
  int* row_cnt_ovf = row_fill + NN;               // NN      -- zero region start
  int* bcnt      = row_cnt_ovf + NN;              // NBUCK*BSTRIDE
  int* ovf_cnt   = bcnt + NBUCK * BSTRIDE;        // 1       -- zero region end
  uint64_t* ovf  = (uint64_t*)(((uintptr_t)(ovf_cnt + 1) + 7) & ~(uintptr_t)7);

  dim3 blk(256);

  hipMemsetAsync(row_cnt_ovf, 0, (size_t)(NN + NBUCK * BSTRIDE + 1) * 4, stream);
  convert_kernel<<<NELEM / 4 / 256, blk, 0, stream>>>((const float4*)q, (ushort4*)xb_q);
  binfill2_kernel<<<NBINBLK, blk, 0, stream>>>(
      rows, cols, vls, bcnt, ovf_cnt, row_cnt_ovf, staging, ovf);
  scan_bsums_kernel<<<1, 512, 0, stream>>>(bcnt, boff);
  scatter_csr2_kernel<<<NBUCK, blk, 0, stream>>>(
      bcnt, boff, row_cnt_ovf, staging, row_ptr, row_fill, csr_cv);
  ovf_drain_kernel<<<1, blk, 0, stream>>>(ovf_cnt, ovf, row_fill, csr_cv);

  const int grid = NN / 4;   // one wave64 per row, 4 rows per block
  spmm_layer_kernel<0><<<grid, blk, 0, stream>>>(
      row_ptr, csr_cv, (const uint32_t*)xb_q, (const float2*)q,
      (uint32_t*)hb1, (float2*)acc, kA[0], kB[0]);
  spmm_layer_kernel<1><<<grid, blk, 0, stream>>>(
      row_ptr, csr_cv, (const uint32_t*)hb1, nullptr,
      (uint32_t*)hb2, (float2*)acc, kA[1], kB[1]);
  spmm_layer_kernel<2><<<grid, blk, 0, stream>>>(
      row_ptr, csr_cv, (const uint32_t*)hb2, nullptr,
      nullptr, (float2*)acc, kA[2], kB[2]);
}

// Round 8
// 445.254 us; speedup vs baseline: 3.7838x; 1.0684x over previous
//
#include <hip/hip_runtime.h>
#include <stdint.h>

#define NN 100000
#define DF 128
#define NE 3200000
#define NELEM (NN * DF)          // 12,800,000
#define NBUCK 391                // row>>8 buckets (max row 99999>>8 = 390)
#define BCAP 12288               // bucket staging capacity (avg ~8184, +45 sigma)
#define BSTRIDE 16               // bcnt padding: one counter per 64B line
#define EPB 4096                 // edges per binfill block (16 per thread)
#define NBINBLK ((NE + EPB - 1) / EPB)   // 782
#define OVF_CAP 65536

// ---------------- Threefry-2x32 (JAX-exact, partitionable, bits = x0^x1) ----
__host__ __device__ __forceinline__ void tf2x32(uint32_t& x0, uint32_t& x1,
                                                uint32_t k0, uint32_t k1) {
  uint32_t ks2 = k0 ^ k1 ^ 0x1BD11BDAu;
  x0 += k0; x1 += k1;
#define TF_RND(r) { x0 += x1; x1 = (x1 << (r)) | (x1 >> (32 - (r))); x1 ^= x0; }
  TF_RND(13) TF_RND(15) TF_RND(26) TF_RND(6)
  x0 += k1;  x1 += ks2 + 1u;
  TF_RND(17) TF_RND(29) TF_RND(16) TF_RND(24)
  x0 += ks2; x1 += k0 + 2u;
  TF_RND(13) TF_RND(15) TF_RND(26) TF_RND(6)
  x0 += k0;  x1 += k1 + 3u;
  TF_RND(17) TF_RND(29) TF_RND(16) TF_RND(24)
  x0 += k1;  x1 += ks2 + 4u;
  TF_RND(13) TF_RND(15) TF_RND(26) TF_RND(6)
  x0 += ks2; x1 += k0 + 5u;
#undef TF_RND
}

__device__ __forceinline__ bool keep_elem(uint32_t kA, uint32_t kB, uint32_t idx) {
  uint32_t x0 = 0u, x1 = idx;          // counter = (hi=0, lo=i)
  tf2x32(x0, x1, kA, kB);
  uint32_t bits = x0 ^ x1;             // partitionable combine (verified r2)
  float u = __uint_as_float((bits >> 9) | 0x3f800000u) - 1.0f;
  return u < 0.9f;
}

// ---------------- bf16 helpers (internal compression only) ----------------
__device__ __forceinline__ uint16_t f2bf(float f) {  // round-to-nearest-even
  uint32_t x = __float_as_uint(f);
  uint32_t r = x + 0x7fffu + ((x >> 16) & 1u);
  return (uint16_t)(r >> 16);
}

// pack: row:17 (bits 47..63) | col:17 (bits 30..46) | (val_bits>>2):30 (bits 0..29)
__device__ __forceinline__ uint64_t pack_edge(int row, int col, float val) {
  return ((uint64_t)(uint32_t)row << 47) | ((uint64_t)(uint32_t)col << 30) |
         (uint64_t)(__float_as_uint(val) >> 2);
}

// CSR record: col:17 (bits 15..31) | val:15 fixed-point m/32768 (bits 0..14)
__device__ __forceinline__ uint32_t pack_csr(int col, float v) {
  int m = (int)(v * 32768.0f + 0.5f);
  if (m > 32767) m = 32767;
  return ((uint32_t)col << 15) | (uint32_t)m;
}

// ============ phase 1: block-local LDS binning, chunked claims ============
__global__ __launch_bounds__(256) void binfill2_kernel(
    const int* __restrict__ rows, const int* __restrict__ cols,
    const float* __restrict__ vals,
    int* __restrict__ bcnt,            // [NBUCK*BSTRIDE], line-padded
    int* __restrict__ ovf_cnt, int* __restrict__ row_cnt_ovf,
    uint64_t* __restrict__ staging, uint64_t* __restrict__ ovf) {
  __shared__ int lcnt[NBUCK];
  __shared__ int lcur[NBUCK];
  int t = threadIdx.x;
  for (int i = t; i < NBUCK; i += 256) lcnt[i] = 0;
  __syncthreads();

  int base = blockIdx.x * EPB;
  int rr[16];
#pragma unroll
  for (int k = 0; k < 16; ++k) {
    int e = base + k * 256 + t;
    rr[k] = (e < NE) ? rows[e] : -1;
    if (rr[k] >= 0) atomicAdd(&lcnt[rr[k] >> 8], 1);
  }
  __syncthreads();
  for (int i = t; i < NBUCK; i += 256)
    lcur[i] = atomicAdd(&bcnt[i * BSTRIDE], lcnt[i]);
  __syncthreads();
#pragma unroll
  for (int k = 0; k < 16; ++k) {
    if (rr[k] < 0) continue;
    int e = base + k * 256 + t;
    int row = rr[k];
    int b = row >> 8;
    uint64_t packed = pack_edge(row, cols[e], vals[e]);
    int slot = atomicAdd(&lcur[b], 1);
    if (slot < BCAP) {
      staging[(size_t)b * BCAP + slot] = packed;
    } else {
      int o = atomicAdd(ovf_cnt, 1);
      if (o < OVF_CAP) ovf[o] = packed;
      atomicAdd(&row_cnt_ovf[row], 1);
    }
  }
}

// ============ bucket-offset scan (391 values, 1 block) ============
__global__ __launch_bounds__(512) void scan_bsums_kernel(const int* __restrict__ bcnt,
                                                         int* __restrict__ boff) {
  __shared__ int lds[512];
  int tid = threadIdx.x;
  int v = (tid < NBUCK) ? bcnt[tid * BSTRIDE] : 0;
  lds[tid] = v;
  __syncthreads();
#pragma unroll
  for (int off = 1; off < 512; off <<= 1) {
    int add = (tid >= off) ? lds[tid - off] : 0;
    __syncthreads();
    lds[tid] += add;
    __syncthreads();
  }
  if (tid < NBUCK) boff[tid] = lds[tid] - v;   // exclusive
}

// ============ phase 2: bucket -> CSR (block b owns rows [b*256, b*256+256)) ====
__global__ __launch_bounds__(256) void scatter_csr2_kernel(
    const int* __restrict__ bcnt, const int* __restrict__ boff,
    const int* __restrict__ row_cnt_ovf,
    const uint64_t* __restrict__ staging,
    int* __restrict__ row_ptr, int* __restrict__ row_fill,
    uint32_t* __restrict__ csr) {
  __shared__ int scnt[256];      // staged count per local row
  __shared__ int lds[256];       // scan workspace
  __shared__ int lcur[256];      // write cursors
  int b = blockIdx.x;
  int t = threadIdx.x;
  int g = b * 256 + t;           // global row
  int n_tot = bcnt[b * BSTRIDE];
  int n_stg = min(n_tot, BCAP);
  const uint64_t* src = staging + (size_t)b * BCAP;

  scnt[t] = 0;
  __syncthreads();
  for (int i = t; i < n_stg; i += 256)
    atomicAdd(&scnt[(int)(src[i] >> 47) & 255], 1);
  __syncthreads();
  int ovfc = (g < NN) ? row_cnt_ovf[g] : 0;
  int v = scnt[t] + ovfc;
  lds[t] = v;
  __syncthreads();
#pragma unroll
  for (int off = 1; off < 256; off <<= 1) {
    int add = (t >= off) ? lds[t - off] : 0;
    __syncthreads();
    lds[t] += add;
    __syncthreads();
  }
  int excl = lds[t] - v;
  int bo = boff[b];
  if (g <= NN) row_ptr[g] = bo + excl;
  if (g < NN) row_fill[g] = bo + excl + scnt[t];
  lcur[t] = excl;
  __syncthreads();
  for (int i = t; i < n_stg; i += 256) {
    uint64_t p = src[i];
    int rl = (int)(p >> 47) & 255;
    int col = (int)((p >> 30) & 0x1FFFFu);
    float vv = __uint_as_float(((uint32_t)p & 0x3FFFFFFFu) << 2);
    int pos = bo + atomicAdd(&lcur[rl], 1);
    csr[pos] = pack_csr(col, vv);
  }
}

// ============ overflow drain (normally 0 edges) ============
__global__ __launch_bounds__(256) void ovf_drain_kernel(
    const int* __restrict__ ovf_cnt, const uint64_t* __restrict__ ovf,
    int* __restrict__ row_fill, uint32_t* __restrict__ csr) {
  int n = min(*ovf_cnt, OVF_CAP);
  for (int i = threadIdx.x; i < n; i += 256) {
    uint64_t p = ovf[i];
    int row = (int)(p >> 47);
    int col = (int)((p >> 30) & 0x1FFFFu);
    float vv = __uint_as_float(((uint32_t)p & 0x3FFFFFFFu) << 2);
    int pos = atomicAdd(&row_fill[row], 1);
    csr[pos] = pack_csr(col, vv);
  }
}

// ---------------- f32 -> bf16 table convert ----------------
__global__ __launch_bounds__(256) void convert_kernel(const float4* __restrict__ src,
                                                      ushort4* __restrict__ dst) {
  int i = blockIdx.x * 256 + threadIdx.x;
  if (i < NELEM / 4) {
    float4 v = src[i];
    dst[i] = make_ushort4(f2bf(v.x), f2bf(v.y), f2bf(v.z), f2bf(v.w));
  }
}

// ============== fused SpMM + residual + dropout ==============
// One wave64 per row; lane owns one bf16x2 dword. Row wave-uniform
// (readfirstlane) => CSR stream s_load'ed, gathers saddr-form.
// MODE 0/1: h = dropout(spmm(x) + x_own); write h (bf16). No acc buffer.
// MODE 2:   h3 in-register; out = (q + h1 + h2 + h3) * 0.25 (f32).
template <int MODE>
__global__ __launch_bounds__(256) void spmm_layer_kernel(
    const int* __restrict__ row_ptr,
    const uint32_t* __restrict__ csr,   // col:17 | val:15 fixed point
    const uint32_t* __restrict__ xb,    // bf16x2 gather table (layer input)
    const uint32_t* __restrict__ qb,    // bf16x2 q (MODE 2)
    const uint32_t* __restrict__ h1b,   // bf16x2 h1 (MODE 2)
    uint32_t* __restrict__ hb_out,      // bf16x2 h out (MODE 0/1)
    float2* __restrict__ outv,          // final output (MODE 2)
    uint32_t kA, uint32_t kB) {
  int r = __builtin_amdgcn_readfirstlane(blockIdx.x * 4 + (threadIdx.x >> 6));
  if (r >= NN) return;                  // grid exact (NN % 4 == 0)
  int lane = threadIdx.x & 63;
  int beg = row_ptr[r], end = row_ptr[r + 1];   // uniform -> scalar loads

  float s0a = 0.f, s1a = 0.f, s0b = 0.f, s1b = 0.f;
  int j = beg;
  int n8 = beg + ((end - beg) & ~7);
  for (; j < n8; j += 8) {              // 8 gathers in flight
    uint32_t cv[8];
#pragma unroll
    for (int u = 0; u < 8; ++u) cv[u] = csr[j + u];   // uniform -> s_load
    uint32_t t[8];
#pragma unroll
    for (int u = 0; u < 8; ++u) {
      const uint32_t* p = xb + (size_t)(cv[u] >> 15) * 64;  // SGPR base
      t[u] = p[lane];                                       // saddr gather
    }
#pragma unroll
    for (int u = 0; u < 8; ++u) {
      float v = (float)(cv[u] & 0x7FFFu) * (1.0f / 32768.0f);
      float lo = __uint_as_float(t[u] << 16);
      float hi = __uint_as_float(t[u] & 0xFFFF0000u);
      if (u & 1) { s0b += v * lo; s1b += v * hi; }
      else       { s0a += v * lo; s1a += v * hi; }
    }
  }
  for (; j < end; ++j) {
    uint32_t cv = csr[j];
    float v = (float)(cv & 0x7FFFu) * (1.0f / 32768.0f);
    const uint32_t* p = xb + (size_t)(cv >> 15) * 64;
    uint32_t t = p[lane];
    s0a += v * __uint_as_float(t << 16);
    s1a += v * __uint_as_float(t & 0xFFFF0000u);
  }
  float s0 = s0a + s0b, s1 = s1a + s1b;

  int oi = r * 64 + lane;
  uint32_t pw = xb[oi];                 // own row = residual source
  float p0 = __uint_as_float(pw << 16);
  float p1 = __uint_as_float(pw & 0xFFFF0000u);

  uint32_t base = (uint32_t)r * 128u + (uint32_t)lane * 2u;
  float t0 = s0 + p0, t1 = s1 + p1;
  float h0 = keep_elem(kA, kB, base)      ? t0 * (1.0f / 0.9f) : 0.0f;
  float h1 = keep_elem(kA, kB, base + 1u) ? t1 * (1.0f / 0.9f) : 0.0f;

  if (MODE < 2) {
    hb_out[oi] = (uint32_t)f2bf(h0) | ((uint32_t)f2bf(h1) << 16);
  } else {
    uint32_t qw = qb[oi];
    uint32_t hw = h1b[oi];
    float q0 = __uint_as_float(qw << 16), q1 = __uint_as_float(qw & 0xFFFF0000u);
    float a0 = __uint_as_float(hw << 16), a1 = __uint_as_float(hw & 0xFFFF0000u);
    // out = (q + h1 + h2 + h3) / 4 ; here p = h2 (own row), h = h3
    outv[oi] = make_float2((q0 + a0 + p0 + h0) * 0.25f,
                           (q1 + a1 + p1 + h1) * 0.25f);
  }
}

// ======================= launch =======================
extern "C" void kernel_launch(void* const* d_in, const int* in_sizes, int n_in,
                              void* d_out, int out_size, void* d_ws, size_t ws_size,
                              hipStream_t stream) {
  const float* q   = (const float*)d_in[0];
  const int* rows  = (const int*)d_in[1];
  const int* cols  = (const int*)d_in[2];
  const float* vls = (const float*)d_in[3];
  float* out = (float*)d_out;

  // layer keys: fold_in(key(42), layer) = threefry2x32((0,42),(0,layer))
  uint32_t kA[3], kB[3];
  for (int l = 0; l < 3; ++l) {
    uint32_t x0 = 0u, x1 = (uint32_t)l;
    tf2x32(x0, x1, 0u, 42u);
    kA[l] = x0; kB[l] = x1;
  }

  // ---- workspace layout (~92 MB) ----
  uint16_t* xb_q = (uint16_t*)d_ws;               // NELEM bf16 (25.6 MB)
  uint16_t* hb1  = xb_q + NELEM;                  // NELEM bf16 (25.6 MB)
  uint16_t* hb2  = hb1 + NELEM;                   // NELEM bf16 (25.6 MB)
  uint64_t* staging = (uint64_t*)hb1;             // 38.4 MB, aliases hb1+hb2 (dead before spmm0)
  uint32_t* csr  = (uint32_t*)(hb2 + NELEM);      // NE u32 (12.8 MB)
  int* row_ptr   = (int*)(csr + NE);              // NN+1
  int* boff      = row_ptr + NN + 1;              // NBUCK
  int* row_fill  = boff + NBUCK;                  // NN
  int* row_cnt_ovf = row_fill + NN;               // NN      -- zero region start
  int* bcnt      = row_cnt_ovf + NN;              // NBUCK*BSTRIDE
  int* ovf_cnt   = bcnt + NBUCK * BSTRIDE;        // 1       -- zero region end
  uint64_t* ovf  = (uint64_t*)(((uintptr_t)(ovf_cnt + 1) + 7) & ~(uintptr_t)7);

  dim3 blk(256);

  hipMemsetAsync(row_cnt_ovf, 0, (size_t)(NN + NBUCK * BSTRIDE + 1) * 4, stream);
  convert_kernel<<<NELEM / 4 / 256, blk, 0, stream>>>((const float4*)q, (ushort4*)xb_q);
  binfill2_kernel<<<NBINBLK, blk, 0, stream>>>(
      rows, cols, vls, bcnt, ovf_cnt, row_cnt_ovf, staging, ovf);
  scan_bsums_kernel<<<1, 512, 0, stream>>>(bcnt, boff);
  scatter_csr2_kernel<<<NBUCK, blk, 0, stream>>>(
      bcnt, boff, row_cnt_ovf, staging, row_ptr, row_fill, csr);
  ovf_drain_kernel<<<1, blk, 0, stream>>>(ovf_cnt, ovf, row_fill, csr);

  const int grid = NN / 4;   // one wave64 per row, 4 rows per block
  spmm_layer_kernel<0><<<grid, blk, 0, stream>>>(
      row_ptr, csr, (const uint32_t*)xb_q, nullptr, nullptr,
      (uint32_t*)hb1, nullptr, kA[0], kB[0]);
  spmm_layer_kernel<1><<<grid, blk, 0, stream>>>(
      row_ptr, csr, (const uint32_t*)hb1, nullptr, nullptr,
      (uint32_t*)hb2, nullptr, kA[1], kB[1]);
  spmm_layer_kernel<2><<<grid, blk, 0, stream>>>(
      row_ptr, csr, (const uint32_t*)hb2, (const uint32_t*)xb_q,
      (const uint32_t*)hb1, nullptr, (float2*)out, kA[2], kB[2]);
}